// Round 16
// baseline (74.767 us; speedup 1.0000x reference)
//
#include <hip/hip_runtime.h>

#define ALPHA 0.2f
#define NN 4096
#define IN_DIM 128
#define REPR 64
#define HEADS 8
#define NCOLP 640   // P stride: 512 num + 8 den @512..519 + 120 pad (not stored)
#define KSPLIT 8
#define PLANE_ELEMS (NN * NCOLP)

typedef _Float16 f16;
typedef _Float16 f16x8 __attribute__((ext_vector_type(8)));
typedef float f32x4 __attribute__((ext_vector_type(4)));

union F16x8U { f16 e[8]; f16x8 v; };

// ws layout (bytes) — ws_size = 256 MiB
#define WS_P   0u            // 8*4096*640*2 = 41943040
#define WS_HID 41943040u     // 8388608
#define WS_F2  50331648u     // 131072
#define WS_MX  50462720u     // 4096 (unused now)
#define WS_A16 50466816u     // 4096*4096*2 = 33554432
#define WS_MT  84021248u     // 768*4096*2 = 6291456 (rows 520..767 unused)
#define WS_END 90312704u

// ---------- k_pre: fused (hidden+f2 | adjacency cvt) ----------
__global__ __launch_bounds__(256) void k_pre(const float* __restrict__ node,
                                             const float* __restrict__ W,
                                             const float* __restrict__ sa,
                                             const float* __restrict__ adj,
                                             float* __restrict__ hidden,
                                             float* __restrict__ f2,
                                             f16* __restrict__ A16) {
  __shared__ float nl[32][137];
  __shared__ __align__(16) float wl[128][64];
  const int t = threadIdx.x;

  if (blockIdx.x >= 1024) {
    const size_t idx = (size_t)(blockIdx.x - 1024) * 256 + t;
    const float4* a4 = (const float4*)adj;
    float4 u = a4[idx*2], w = a4[idx*2+1];
    F16x8U o;
    o.e[0]=(f16)u.x; o.e[1]=(f16)u.y; o.e[2]=(f16)u.z; o.e[3]=(f16)u.w;
    o.e[4]=(f16)w.x; o.e[5]=(f16)w.y; o.e[6]=(f16)w.z; o.e[7]=(f16)w.w;
    *(f16x8*)&A16[idx*8] = o.v;
    return;
  }

  const int i = blockIdx.x >> 7;
  const int jb = (blockIdx.x & 127) * 32;
  const float4* gn = (const float4*)(node + (size_t)jb * IN_DIM);
  #pragma unroll
  for (int q = 0; q < 4; ++q) {
    int i4 = q * 256 + t;
    int r = i4 >> 5, c4 = i4 & 31;
    float4 v = gn[i4];
    nl[r][c4*4+0] = v.x; nl[r][c4*4+1] = v.y; nl[r][c4*4+2] = v.z; nl[r][c4*4+3] = v.w;
  }
  const float4* gw = (const float4*)(W + (size_t)i * IN_DIM * REPR);
  #pragma unroll
  for (int q = 0; q < 8; ++q) {
    int i4 = q * 256 + t;
    int r = i4 >> 4, c4 = i4 & 15;
    *(float4*)&wl[r][c4*4] = gw[i4];
  }
  __syncthreads();
  const int tx = t & 15, ty = t >> 4;
  float acc0[4] = {0,0,0,0}, acc1[4] = {0,0,0,0};
  #pragma unroll 4
  for (int k = 0; k < 128; ++k) {
    float a0 = nl[2*ty][k], a1 = nl[2*ty+1][k];
    float4 b = *(const float4*)&wl[k][4*tx];
    acc0[0] += a0*b.x; acc0[1] += a0*b.y; acc0[2] += a0*b.z; acc0[3] += a0*b.w;
    acc1[0] += a1*b.x; acc1[1] += a1*b.y; acc1[2] += a1*b.z; acc1[3] += a1*b.w;
  }
  float* o0 = hidden + ((size_t)i*NN + jb + 2*ty) * REPR + 4*tx;
  *(float4*)o0 = make_float4(acc0[0],acc0[1],acc0[2],acc0[3]);
  *(float4*)(o0 + REPR) = make_float4(acc1[0],acc1[1],acc1[2],acc1[3]);

  float4 ad = *(const float4*)(sa + i * 2 * REPR + REPR + 4*tx);
  float s0 = 0.f, s1 = 0.f, x;
  x = acc0[0]; s0 += (x > 0.f ? x : ALPHA*x) * ad.x;
  x = acc0[1]; s0 += (x > 0.f ? x : ALPHA*x) * ad.y;
  x = acc0[2]; s0 += (x > 0.f ? x : ALPHA*x) * ad.z;
  x = acc0[3]; s0 += (x > 0.f ? x : ALPHA*x) * ad.w;
  x = acc1[0]; s1 += (x > 0.f ? x : ALPHA*x) * ad.x;
  x = acc1[1]; s1 += (x > 0.f ? x : ALPHA*x) * ad.y;
  x = acc1[2]; s1 += (x > 0.f ? x : ALPHA*x) * ad.z;
  x = acc1[3]; s1 += (x > 0.f ? x : ALPHA*x) * ad.w;
  #pragma unroll
  for (int d = 8; d > 0; d >>= 1) {
    s0 += __shfl_down(s0, d, 16);
    s1 += __shfl_down(s1, d, 16);
  }
  if (tx == 0) {
    f2[i*NN + jb + 2*ty]     = s0;
    f2[i*NN + jb + 2*ty + 1] = s1;
  }
}

// ---------- k_mt (fused per-head max): num rows (y<128) + den rows (y==128) ----------
__global__ __launch_bounds__(256) void k_mt(const float* __restrict__ hidden,
                                            const float* __restrict__ f2,
                                            f16* __restrict__ MT) {
  __shared__ float red[256];
  const int i = blockIdx.x;
  const int t = threadIdx.x;
  // recompute per-head max from L2-hot f2 (replaces the k_max kernel)
  float mm = -1e30f;
  #pragma unroll
  for (int q = 0; q < 16; ++q) mm = fmaxf(mm, f2[i*NN + q*256 + t]);
  red[t] = mm; __syncthreads();
  for (int s = 128; s > 0; s >>= 1) {
    if (t < s) red[t] = fmaxf(red[t], red[t + s]);
    __syncthreads();
  }
  const float m = red[0];

  if (blockIdx.y < 128) {
    const int l = t & 63, q = t >> 6;
    const int k0 = blockIdx.y * 32 + q * 8;
    float g[8];
    #pragma unroll
    for (int kk = 0; kk < 8; ++kk) g[kk] = __expf(f2[i*NN + k0 + kk] - m);
    F16x8U u;
    #pragma unroll
    for (int kk = 0; kk < 8; ++kk) {
      float h = hidden[((size_t)i*NN + k0 + kk) * REPR + l];
      u.e[kk] = (f16)(g[kk] * h);
    }
    *(f16x8*)&MT[(size_t)(i*REPR + l) * NN + k0] = u.v;
  } else {
    #pragma unroll
    for (int q = 0; q < 2; ++q) {
      const int k0 = (t * 2 + q) * 8;
      F16x8U u;
      #pragma unroll
      for (int kk = 0; kk < 8; ++kk) u.e[kk] = (f16)__expf(f2[i*NN + k0 + kk] - m);
      *(f16x8*)&MT[(size_t)(512 + i) * NN + k0] = u.v;
    }
  }
}

// ---------- k6: 256x320 GEMM, BK=32, TRIPLE buffer, 2-deep counted vmcnt ----------
// P[z][j][c] = sum_{k in split z} A16[j,k] * MT[c,k].  Grid 256 (one balanced
// round). 3 LDS buffers (108KB): stage tile kt+2 while computing kt -> 2 tiles
// (8-10 loads/thread) in flight; per-wave counted waits (waves 0-3 stage 5
// chunks/tile, waves 4-7 stage 4). 64B rows packed as 2-row super-rows
// (128B, 8-slot XOR) -> same bank distribution as R15's zero-conflict layout.
__global__ __launch_bounds__(512) void k_gemm(const f16* __restrict__ A16,
                                              const f16* __restrict__ MT,
                                              f16* __restrict__ P) {
  __shared__ __align__(16) f16 smA[3][256*32];   // 3 x 16 KB
  __shared__ __align__(16) f16 smB[3][320*32];   // 3 x 20 KB
  const int t = threadIdx.x;
  const int lane = t & 63, wid = t >> 6;         // wid 0..7

  const int lin = blockIdx.x;                    // 0..255
  const int xcd = lin & 7, idx = lin >> 3;       // idx 0..31
  const int jt  = xcd + 8 * (idx / 16);          // 0..15
  const int r   = idx % 16;
  const int ct  = r & 1;                         // 0..1
  const int zt  = r >> 1;                        // 0..7

  const int j0 = jt * 256;
  const int c0 = ct * 320;
  const int kz = zt * 512;                       // 16 K-tiles of 32
  const int NK = 16;

  const char* Ab = (const char*)A16;
  const char* Bb = (const char*)MT;

  // A staging: 1024 chunks (2/thread). chunk ci -> super-row sr=ci>>3, phys
  // slot p=ci&7; logical s = p^(sr&7); h=s>>2 (row parity), kc=s&3 (k-chunk).
  size_t ga[2]; int cbA[2];
  #pragma unroll
  for (int q = 0; q < 2; ++q) {
    int ci = q*512 + t;
    int sr = ci >> 3, p = ci & 7;
    int s = p ^ (sr & 7);
    int row = 2*sr + (s >> 2), kc = s & 3;
    ga[q]  = ((size_t)(j0 + row) * NN + kz) * 2 + (size_t)kc * 16;
    cbA[q] = (q*512 + wid*64) * 16;
  }
  // B staging: 1280 chunks. q=0,1: all waves (2/thread); q=2: waves 0-3 only.
  size_t gb[3]; int cbB[3];
  #pragma unroll
  for (int q = 0; q < 3; ++q) {
    int ci = (q < 2) ? (q*512 + t) : (1024 + (t & 255));
    int sr = ci >> 3, p = ci & 7;
    int s = p ^ (sr & 7);
    int row = 2*sr + (s >> 2), kc = s & 3;
    gb[q]  = ((size_t)(c0 + row) * NN + kz) * 2 + (size_t)kc * 16;
    cbB[q] = (q < 2) ? (q*512 + wid*64) * 16 : (1024 + wid*64) * 16;
  }

  const int frow = lane & 15, kg = lane >> 4;
  const int wr = wid >> 2, wc = wid & 3;         // 2 x 4 wave grid
  int aoff[8], boff[5];
  #pragma unroll
  for (int mi = 0; mi < 8; ++mi) {
    int row = wr*128 + mi*16 + frow;
    int sr = row >> 1;
    int p = (((row & 1) << 2) | kg) ^ (sr & 7);
    aoff[mi] = sr*128 + p*16;                    // bytes
  }
  #pragma unroll
  for (int ni = 0; ni < 5; ++ni) {
    int row = wc*80 + ni*16 + frow;
    int sr = row >> 1;
    int p = (((row & 1) << 2) | kg) ^ (sr & 7);
    boff[ni] = sr*128 + p*16;                    // bytes
  }

#define STAGE(B, KT) do { \
    const size_t kb_ = (size_t)(KT) * 64;  /* 32 f16 */ \
    char* dA_ = (char*)smA + (B) * 16384; \
    char* dB_ = (char*)smB + (B) * 20480; \
    _Pragma("unroll") \
    for (int q = 0; q < 2; ++q) \
      __builtin_amdgcn_global_load_lds( \
        (const __attribute__((address_space(1))) void*)(Ab + ga[q] + kb_), \
        (__attribute__((address_space(3))) void*)(dA_ + cbA[q]), 16, 0, 0); \
    _Pragma("unroll") \
    for (int q = 0; q < 2; ++q) \
      __builtin_amdgcn_global_load_lds( \
        (const __attribute__((address_space(1))) void*)(Bb + gb[q] + kb_), \
        (__attribute__((address_space(3))) void*)(dB_ + cbB[q]), 16, 0, 0); \
    if (wid < 4) \
      __builtin_amdgcn_global_load_lds( \
        (const __attribute__((address_space(1))) void*)(Bb + gb[2] + kb_), \
        (__attribute__((address_space(3))) void*)(dB_ + cbB[2]), 16, 0, 0); \
  } while (0)

  f32x4 acc[8][5] = {};

  // prologue: tiles 0,1 in flight
  STAGE(0, 0);
  STAGE(1, 1);

  int b0 = 0, b1 = 1, b2 = 2;
  #pragma unroll 1
  for (int kt = 0; kt < NK; ++kt) {
    if (kt + 2 < NK) {
      STAGE(b2, kt + 2);
      if (wid < 4) asm volatile("s_waitcnt vmcnt(10)" ::: "memory");
      else         asm volatile("s_waitcnt vmcnt(8)"  ::: "memory");
    } else if (kt + 1 < NK) {
      if (wid < 4) asm volatile("s_waitcnt vmcnt(5)" ::: "memory");
      else         asm volatile("s_waitcnt vmcnt(4)" ::: "memory");
    } else {
      asm volatile("s_waitcnt vmcnt(0)" ::: "memory");
    }
    __builtin_amdgcn_s_barrier();
    const char* bufA = (const char*)smA + b0 * 16384;
    const char* bufB = (const char*)smB + b0 * 20480;
    f16x8 a[8], b[5];
    #pragma unroll
    for (int mi = 0; mi < 8; ++mi)
      a[mi] = *(const f16x8*)(bufA + aoff[mi]);
    #pragma unroll
    for (int ni = 0; ni < 5; ++ni)
      b[ni] = *(const f16x8*)(bufB + boff[ni]);
    #pragma unroll
    for (int mi = 0; mi < 8; ++mi)
      #pragma unroll
      for (int ni = 0; ni < 5; ++ni)
        acc[mi][ni] = __builtin_amdgcn_mfma_f32_16x16x32_f16(a[mi], b[ni], acc[mi][ni], 0, 0, 0);
    __builtin_amdgcn_s_barrier();
    int tmp = b0; b0 = b1; b1 = b2; b2 = tmp;
  }

  f16* Pz = P + (size_t)zt * PLANE_ELEMS;
  #pragma unroll
  for (int mi = 0; mi < 8; ++mi) {
    const int orow = j0 + wr*128 + mi*16 + kg*4;
    #pragma unroll
    for (int ni = 0; ni < 5; ++ni) {
      const int ocol = c0 + wc*80 + ni*16 + frow;
      if (ocol < 520) {
        #pragma unroll
        for (int r4 = 0; r4 < 4; ++r4)
          Pz[(size_t)(orow + r4) * NCOLP + ocol] = (f16)acc[mi][ni][r4];
      }
    }
  }
#undef STAGE
}

// ---------- k7: out[j, i*64+l] = num/den over 8 split-K planes ----------
__global__ __launch_bounds__(256) void k_div(const f16* __restrict__ P,
                                             float* __restrict__ out) {
  const int gid = blockIdx.x * 256 + threadIdx.x;   // 2,097,152
  const int j = gid >> 9, c = gid & 511, i = c >> 6;
  const size_t rc = (size_t)j*NCOLP + c;
  const size_t rd = (size_t)j*NCOLP + 512 + i;
  float num = 0.f, den = 0.f;
  #pragma unroll
  for (int z = 0; z < KSPLIT; ++z) {
    const f16* Pz = P + (size_t)z * PLANE_ELEMS;
    num += (float)Pz[rc];
    den += (float)Pz[rd];
  }
  out[gid] = num / den;
}

extern "C" void kernel_launch(void* const* d_in, const int* in_sizes, int n_in,
                              void* d_out, int out_size, void* d_ws, size_t ws_size,
                              hipStream_t stream) {
  const float* node = (const float*)d_in[0];
  const float* adj  = (const float*)d_in[1];
  const float* W    = (const float*)d_in[2];
  const float* sa   = (const float*)d_in[3];
  float* out = (float*)d_out;
  char* ws = (char*)d_ws;
  if (ws_size < (size_t)WS_END) return;

  float* hidden = (float*)(ws + WS_HID);
  float* f2     = (float*)(ws + WS_F2);
  f16*   A16    = (f16*)(ws + WS_A16);
  f16*   MT     = (f16*)(ws + WS_MT);
  f16*   P      = (f16*)(ws + WS_P);

  k_pre   <<<dim3(9216),      256, 0, stream>>>(node, W, sa, adj, hidden, f2, A16);
  k_mt    <<<dim3(8, 129),    256, 0, stream>>>(hidden, f2, MT);
  k_gemm  <<<dim3(256),       512, 0, stream>>>(A16, MT, P);
  k_div   <<<dim3(8192),      256, 0, stream>>>(P, out);
}

// Round 17
// 69.288 us; speedup vs baseline: 1.0791x; 1.0791x over previous
//
#include <hip/hip_runtime.h>

#define ALPHA 0.2f
#define NN 4096
#define IN_DIM 128
#define REPR 64
#define HEADS 8
#define NCOLP 640   // P stride: 512 num + 8 den @512..519 + 120 pad (not stored)
#define KSPLIT 8
#define PLANE_ELEMS (NN * NCOLP)

typedef _Float16 f16;
typedef _Float16 f16x8 __attribute__((ext_vector_type(8)));
typedef float f32x4 __attribute__((ext_vector_type(4)));

union F16x8U { f16 e[8]; f16x8 v; };

// ws layout (bytes) — ws_size = 256 MiB
#define WS_P   0u            // 8*4096*640*2 = 41943040
#define WS_HID 41943040u     // 8388608
#define WS_F2  50331648u     // 131072
#define WS_A16 50466816u     // 4096*4096*2 = 33554432
#define WS_MT  84021248u     // 768*4096*2 = 6291456 (rows 520..767 unused)
#define WS_END 90312704u

// ---------- k_pre: fused (hidden+f2 | adjacency cvt) ----------
__global__ __launch_bounds__(256) void k_pre(const float* __restrict__ node,
                                             const float* __restrict__ W,
                                             const float* __restrict__ sa,
                                             const float* __restrict__ adj,
                                             float* __restrict__ hidden,
                                             float* __restrict__ f2,
                                             f16* __restrict__ A16) {
  __shared__ float nl[32][137];
  __shared__ __align__(16) float wl[128][64];
  const int t = threadIdx.x;

  if (blockIdx.x >= 1024) {
    const size_t idx = (size_t)(blockIdx.x - 1024) * 256 + t;
    const float4* a4 = (const float4*)adj;
    float4 u = a4[idx*2], w = a4[idx*2+1];
    F16x8U o;
    o.e[0]=(f16)u.x; o.e[1]=(f16)u.y; o.e[2]=(f16)u.z; o.e[3]=(f16)u.w;
    o.e[4]=(f16)w.x; o.e[5]=(f16)w.y; o.e[6]=(f16)w.z; o.e[7]=(f16)w.w;
    *(f16x8*)&A16[idx*8] = o.v;
    return;
  }

  const int i = blockIdx.x >> 7;
  const int jb = (blockIdx.x & 127) * 32;
  const float4* gn = (const float4*)(node + (size_t)jb * IN_DIM);
  #pragma unroll
  for (int q = 0; q < 4; ++q) {
    int i4 = q * 256 + t;
    int r = i4 >> 5, c4 = i4 & 31;
    float4 v = gn[i4];
    nl[r][c4*4+0] = v.x; nl[r][c4*4+1] = v.y; nl[r][c4*4+2] = v.z; nl[r][c4*4+3] = v.w;
  }
  const float4* gw = (const float4*)(W + (size_t)i * IN_DIM * REPR);
  #pragma unroll
  for (int q = 0; q < 8; ++q) {
    int i4 = q * 256 + t;
    int r = i4 >> 4, c4 = i4 & 15;
    *(float4*)&wl[r][c4*4] = gw[i4];
  }
  __syncthreads();
  const int tx = t & 15, ty = t >> 4;
  float acc0[4] = {0,0,0,0}, acc1[4] = {0,0,0,0};
  #pragma unroll 4
  for (int k = 0; k < 128; ++k) {
    float a0 = nl[2*ty][k], a1 = nl[2*ty+1][k];
    float4 b = *(const float4*)&wl[k][4*tx];
    acc0[0] += a0*b.x; acc0[1] += a0*b.y; acc0[2] += a0*b.z; acc0[3] += a0*b.w;
    acc1[0] += a1*b.x; acc1[1] += a1*b.y; acc1[2] += a1*b.z; acc1[3] += a1*b.w;
  }
  float* o0 = hidden + ((size_t)i*NN + jb + 2*ty) * REPR + 4*tx;
  *(float4*)o0 = make_float4(acc0[0],acc0[1],acc0[2],acc0[3]);
  *(float4*)(o0 + REPR) = make_float4(acc1[0],acc1[1],acc1[2],acc1[3]);

  float4 ad = *(const float4*)(sa + i * 2 * REPR + REPR + 4*tx);
  float s0 = 0.f, s1 = 0.f, x;
  x = acc0[0]; s0 += (x > 0.f ? x : ALPHA*x) * ad.x;
  x = acc0[1]; s0 += (x > 0.f ? x : ALPHA*x) * ad.y;
  x = acc0[2]; s0 += (x > 0.f ? x : ALPHA*x) * ad.z;
  x = acc0[3]; s0 += (x > 0.f ? x : ALPHA*x) * ad.w;
  x = acc1[0]; s1 += (x > 0.f ? x : ALPHA*x) * ad.x;
  x = acc1[1]; s1 += (x > 0.f ? x : ALPHA*x) * ad.y;
  x = acc1[2]; s1 += (x > 0.f ? x : ALPHA*x) * ad.z;
  x = acc1[3]; s1 += (x > 0.f ? x : ALPHA*x) * ad.w;
  #pragma unroll
  for (int d = 8; d > 0; d >>= 1) {
    s0 += __shfl_down(s0, d, 16);
    s1 += __shfl_down(s1, d, 16);
  }
  if (tx == 0) {
    f2[i*NN + jb + 2*ty]     = s0;
    f2[i*NN + jb + 2*ty + 1] = s1;
  }
}

// ---------- k_mt (fused per-head max): num rows (y<128) + den rows (y==128) ----------
__global__ __launch_bounds__(256) void k_mt(const float* __restrict__ hidden,
                                            const float* __restrict__ f2,
                                            f16* __restrict__ MT) {
  __shared__ float red[256];
  const int i = blockIdx.x;
  const int t = threadIdx.x;
  float mm = -1e30f;
  #pragma unroll
  for (int q = 0; q < 16; ++q) mm = fmaxf(mm, f2[i*NN + q*256 + t]);
  red[t] = mm; __syncthreads();
  for (int s = 128; s > 0; s >>= 1) {
    if (t < s) red[t] = fmaxf(red[t], red[t + s]);
    __syncthreads();
  }
  const float m = red[0];

  if (blockIdx.y < 128) {
    const int l = t & 63, q = t >> 6;
    const int k0 = blockIdx.y * 32 + q * 8;
    float g[8];
    #pragma unroll
    for (int kk = 0; kk < 8; ++kk) g[kk] = __expf(f2[i*NN + k0 + kk] - m);
    F16x8U u;
    #pragma unroll
    for (int kk = 0; kk < 8; ++kk) {
      float h = hidden[((size_t)i*NN + k0 + kk) * REPR + l];
      u.e[kk] = (f16)(g[kk] * h);
    }
    *(f16x8*)&MT[(size_t)(i*REPR + l) * NN + k0] = u.v;
  } else {
    #pragma unroll
    for (int q = 0; q < 2; ++q) {
      const int k0 = (t * 2 + q) * 8;
      F16x8U u;
      #pragma unroll
      for (int kk = 0; kk < 8; ++kk) u.e[kk] = (f16)__expf(f2[i*NN + k0 + kk] - m);
      *(f16x8*)&MT[(size_t)(512 + i) * NN + k0] = u.v;
    }
  }
}

// ---------- k6: 256x320-tile GEMM, counted-vmcnt dbuf, grid EXACTLY 256 (R15) ----------
__global__ __launch_bounds__(512) void k_gemm(const f16* __restrict__ A16,
                                              const f16* __restrict__ MT,
                                              f16* __restrict__ P) {
  __shared__ __align__(16) f16 smA[2][256*64];   // 2 x 32 KB
  __shared__ __align__(16) f16 smB[2][320*64];   // 2 x 40 KB
  const int t = threadIdx.x;
  const int lane = t & 63, wid = t >> 6;         // wid 0..7

  const int lin = blockIdx.x;                    // 0..255
  const int xcd = lin & 7, idx = lin >> 3;       // idx 0..31
  const int jt  = xcd + 8 * (idx / 16);          // 0..15
  const int r   = idx % 16;
  const int ct  = r & 1;                         // 0..1
  const int zt  = r >> 1;                        // 0..7

  const int j0 = jt * 256;
  const int c0 = ct * 320;
  const int kz = zt * 512;                       // 8 K-tiles of 64
  const int NK = 8;

  const char* Ab = (const char*)A16;
  const char* Bb = (const char*)MT;
  size_t ga[4]; int cbA[4];
  #pragma unroll
  for (int q = 0; q < 4; ++q) {                  // A: 2048 chunks, 4/thread
    int ci = q*512 + t;
    int m = ci >> 3, s = ci & 7;
    int c = s ^ (m & 7);
    ga[q]  = ((size_t)(j0 + m) * NN + kz) * 2 + (size_t)c * 16;
    cbA[q] = (q*512 + wid*64) * 16;
  }
  size_t gb[5]; int cbB[5];
  #pragma unroll
  for (int q = 0; q < 5; ++q) {                  // B: 2560 chunks, 5/thread
    int ci = q*512 + t;
    int m = ci >> 3, s = ci & 7;
    int c = s ^ (m & 7);
    gb[q]  = ((size_t)(c0 + m) * NN + kz) * 2 + (size_t)c * 16;
    cbB[q] = (q*512 + wid*64) * 16;
  }

  const int frow = lane & 15, kg = lane >> 4;
  const int wr = wid >> 2, wc = wid & 3;         // 2 x 4 wave grid
  int arow[8], brow[5], soff[2];
  #pragma unroll
  for (int mi = 0; mi < 8; ++mi) arow[mi] = (wr*128 + mi*16 + frow) * 128; // bytes
  #pragma unroll
  for (int ni = 0; ni < 5; ++ni) brow[ni] = (wc*80 + ni*16 + frow) * 128;  // bytes
  #pragma unroll
  for (int kk = 0; kk < 2; ++kk) soff[kk] = ((kk*4 + kg) ^ (frow & 7)) * 16;

#define STAGE(BUF, KT) do { \
    const size_t kb_ = (size_t)(KT) * 128;  /* 64 f16 */ \
    _Pragma("unroll") \
    for (int q = 0; q < 4; ++q) \
      __builtin_amdgcn_global_load_lds( \
        (const __attribute__((address_space(1))) void*)(Ab + ga[q] + kb_), \
        (__attribute__((address_space(3))) void*)((char*)smA[BUF] + cbA[q]), 16, 0, 0); \
    _Pragma("unroll") \
    for (int q = 0; q < 5; ++q) \
      __builtin_amdgcn_global_load_lds( \
        (const __attribute__((address_space(1))) void*)(Bb + gb[q] + kb_), \
        (__attribute__((address_space(3))) void*)((char*)smB[BUF] + cbB[q]), 16, 0, 0); \
  } while (0)

  f32x4 acc[8][5] = {};

  STAGE(0, 0);
  #pragma unroll 1
  for (int kt = 0; kt < NK; ++kt) {
    const int cur = kt & 1;
    if (kt + 1 < NK) {
      STAGE(cur ^ 1, kt + 1);
      asm volatile("s_waitcnt vmcnt(9)" ::: "memory");   // kt landed, kt+1 in flight
    } else {
      asm volatile("s_waitcnt vmcnt(0)" ::: "memory");
    }
    __builtin_amdgcn_s_barrier();
    const char* bufA = (const char*)smA[cur];
    const char* bufB = (const char*)smB[cur];
    #pragma unroll
    for (int kk = 0; kk < 2; ++kk) {
      f16x8 a[8], b[5];
      #pragma unroll
      for (int mi = 0; mi < 8; ++mi)
        a[mi] = *(const f16x8*)(bufA + arow[mi] + soff[kk]);
      #pragma unroll
      for (int ni = 0; ni < 5; ++ni)
        b[ni] = *(const f16x8*)(bufB + brow[ni] + soff[kk]);
      #pragma unroll
      for (int mi = 0; mi < 8; ++mi)
        #pragma unroll
        for (int ni = 0; ni < 5; ++ni)
          acc[mi][ni] = __builtin_amdgcn_mfma_f32_16x16x32_f16(a[mi], b[ni], acc[mi][ni], 0, 0, 0);
    }
    __builtin_amdgcn_s_barrier();
  }

  f16* Pz = P + (size_t)zt * PLANE_ELEMS;
  #pragma unroll
  for (int mi = 0; mi < 8; ++mi) {
    const int orow = j0 + wr*128 + mi*16 + kg*4;
    #pragma unroll
    for (int ni = 0; ni < 5; ++ni) {
      const int ocol = c0 + wc*80 + ni*16 + frow;
      if (ocol < 520) {
        #pragma unroll
        for (int r4 = 0; r4 < 4; ++r4)
          Pz[(size_t)(orow + r4) * NCOLP + ocol] = (f16)acc[mi][ni][r4];
      }
    }
  }
#undef STAGE
}

// ---------- k7: vectorized div — 8 cols/thread, f16x8 plane loads ----------
__global__ __launch_bounds__(256) void k_div(const f16* __restrict__ P,
                                             float* __restrict__ out) {
  const int gid = blockIdx.x * 256 + threadIdx.x;   // 262,144
  const int j = gid >> 6, c8 = gid & 63;            // row, 8-col group
  const int i = c8 >> 3;                            // head of this col group
  const size_t rc = (size_t)j*NCOLP + c8*8;
  const size_t rd = (size_t)j*NCOLP + 512 + i;
  float num[8] = {0,0,0,0,0,0,0,0};
  float den = 0.f;
  #pragma unroll
  for (int z = 0; z < KSPLIT; ++z) {
    const f16* Pz = P + (size_t)z * PLANE_ELEMS;
    f16x8 v = *(const f16x8*)&Pz[rc];
    #pragma unroll
    for (int e = 0; e < 8; ++e) num[e] += (float)v[e];
    den += (float)Pz[rd];
  }
  const float inv = 1.f / den;
  float4 o0 = make_float4(num[0]*inv, num[1]*inv, num[2]*inv, num[3]*inv);
  float4 o1 = make_float4(num[4]*inv, num[5]*inv, num[6]*inv, num[7]*inv);
  float* ob = out + (size_t)j*512 + c8*8;
  *(float4*)ob = o0;
  *(float4*)(ob + 4) = o1;
}

extern "C" void kernel_launch(void* const* d_in, const int* in_sizes, int n_in,
                              void* d_out, int out_size, void* d_ws, size_t ws_size,
                              hipStream_t stream) {
  const float* node = (const float*)d_in[0];
  const float* adj  = (const float*)d_in[1];
  const float* W    = (const float*)d_in[2];
  const float* sa   = (const float*)d_in[3];
  float* out = (float*)d_out;
  char* ws = (char*)d_ws;
  if (ws_size < (size_t)WS_END) return;

  float* hidden = (float*)(ws + WS_HID);
  float* f2     = (float*)(ws + WS_F2);
  f16*   A16    = (f16*)(ws + WS_A16);
  f16*   MT     = (f16*)(ws + WS_MT);
  f16*   P      = (f16*)(ws + WS_P);

  k_pre   <<<dim3(9216),      256, 0, stream>>>(node, W, sa, adj, hidden, f2, A16);
  k_mt    <<<dim3(8, 129),    256, 0, stream>>>(hidden, f2, MT);
  k_gemm  <<<dim3(256),       512, 0, stream>>>(A16, MT, P);
  k_div   <<<dim3(1024),      256, 0, stream>>>(P, out);
}

// Round 18
// 68.477 us; speedup vs baseline: 1.0918x; 1.0118x over previous
//
#include <hip/hip_runtime.h>

#define ALPHA 0.2f
#define NN 4096
#define IN_DIM 128
#define REPR 64
#define HEADS 8
#define NCOLP 640   // P stride: 512 num + 8 den @512..519 + 120 pad (not stored)
#define KSPLIT 8
#define PLANE_ELEMS (NN * NCOLP)

typedef _Float16 f16;
typedef _Float16 f16x8 __attribute__((ext_vector_type(8)));
typedef float f32x4 __attribute__((ext_vector_type(4)));

union F16x8U { f16 e[8]; f16x8 v; };

// ws layout (bytes) — ws_size = 256 MiB
#define WS_P   0u            // 8*4096*640*2 = 41943040
#define WS_HID 41943040u     // 8388608
#define WS_F2  50331648u     // 131072
#define WS_A16 50466816u     // 4096*4096*2 = 33554432
#define WS_MT  84021248u     // 768*4096*2 = 6291456 (rows 520..767 unused)
#define WS_END 90312704u

// ---------- k_pre: fused (hidden+f2 | adjacency cvt) ----------
__global__ __launch_bounds__(256) void k_pre(const float* __restrict__ node,
                                             const float* __restrict__ W,
                                             const float* __restrict__ sa,
                                             const float* __restrict__ adj,
                                             float* __restrict__ hidden,
                                             float* __restrict__ f2,
                                             f16* __restrict__ A16) {
  __shared__ float nl[32][137];
  __shared__ __align__(16) float wl[128][64];
  const int t = threadIdx.x;

  if (blockIdx.x >= 1024) {
    const size_t idx = (size_t)(blockIdx.x - 1024) * 256 + t;
    const float4* a4 = (const float4*)adj;
    float4 u = a4[idx*2], w = a4[idx*2+1];
    F16x8U o;
    o.e[0]=(f16)u.x; o.e[1]=(f16)u.y; o.e[2]=(f16)u.z; o.e[3]=(f16)u.w;
    o.e[4]=(f16)w.x; o.e[5]=(f16)w.y; o.e[6]=(f16)w.z; o.e[7]=(f16)w.w;
    *(f16x8*)&A16[idx*8] = o.v;
    return;
  }

  const int i = blockIdx.x >> 7;
  const int jb = (blockIdx.x & 127) * 32;
  const float4* gn = (const float4*)(node + (size_t)jb * IN_DIM);
  #pragma unroll
  for (int q = 0; q < 4; ++q) {
    int i4 = q * 256 + t;
    int r = i4 >> 5, c4 = i4 & 31;
    float4 v = gn[i4];
    nl[r][c4*4+0] = v.x; nl[r][c4*4+1] = v.y; nl[r][c4*4+2] = v.z; nl[r][c4*4+3] = v.w;
  }
  const float4* gw = (const float4*)(W + (size_t)i * IN_DIM * REPR);
  #pragma unroll
  for (int q = 0; q < 8; ++q) {
    int i4 = q * 256 + t;
    int r = i4 >> 4, c4 = i4 & 15;
    *(float4*)&wl[r][c4*4] = gw[i4];
  }
  __syncthreads();
  const int tx = t & 15, ty = t >> 4;
  float acc0[4] = {0,0,0,0}, acc1[4] = {0,0,0,0};
  #pragma unroll 4
  for (int k = 0; k < 128; ++k) {
    float a0 = nl[2*ty][k], a1 = nl[2*ty+1][k];
    float4 b = *(const float4*)&wl[k][4*tx];
    acc0[0] += a0*b.x; acc0[1] += a0*b.y; acc0[2] += a0*b.z; acc0[3] += a0*b.w;
    acc1[0] += a1*b.x; acc1[1] += a1*b.y; acc1[2] += a1*b.z; acc1[3] += a1*b.w;
  }
  float* o0 = hidden + ((size_t)i*NN + jb + 2*ty) * REPR + 4*tx;
  *(float4*)o0 = make_float4(acc0[0],acc0[1],acc0[2],acc0[3]);
  *(float4*)(o0 + REPR) = make_float4(acc1[0],acc1[1],acc1[2],acc1[3]);

  float4 ad = *(const float4*)(sa + i * 2 * REPR + REPR + 4*tx);
  float s0 = 0.f, s1 = 0.f, x;
  x = acc0[0]; s0 += (x > 0.f ? x : ALPHA*x) * ad.x;
  x = acc0[1]; s0 += (x > 0.f ? x : ALPHA*x) * ad.y;
  x = acc0[2]; s0 += (x > 0.f ? x : ALPHA*x) * ad.z;
  x = acc0[3]; s0 += (x > 0.f ? x : ALPHA*x) * ad.w;
  x = acc1[0]; s1 += (x > 0.f ? x : ALPHA*x) * ad.x;
  x = acc1[1]; s1 += (x > 0.f ? x : ALPHA*x) * ad.y;
  x = acc1[2]; s1 += (x > 0.f ? x : ALPHA*x) * ad.z;
  x = acc1[3]; s1 += (x > 0.f ? x : ALPHA*x) * ad.w;
  #pragma unroll
  for (int d = 8; d > 0; d >>= 1) {
    s0 += __shfl_down(s0, d, 16);
    s1 += __shfl_down(s1, d, 16);
  }
  if (tx == 0) {
    f2[i*NN + jb + 2*ty]     = s0;
    f2[i*NN + jb + 2*ty + 1] = s1;
  }
}

// ---------- k_mt (fused per-head max): num rows (y<128) + den rows (y==128) ----------
__global__ __launch_bounds__(256) void k_mt(const float* __restrict__ hidden,
                                            const float* __restrict__ f2,
                                            f16* __restrict__ MT) {
  __shared__ float red[256];
  const int i = blockIdx.x;
  const int t = threadIdx.x;
  float mm = -1e30f;
  #pragma unroll
  for (int q = 0; q < 16; ++q) mm = fmaxf(mm, f2[i*NN + q*256 + t]);
  red[t] = mm; __syncthreads();
  for (int s = 128; s > 0; s >>= 1) {
    if (t < s) red[t] = fmaxf(red[t], red[t + s]);
    __syncthreads();
  }
  const float m = red[0];

  if (blockIdx.y < 128) {
    const int l = t & 63, q = t >> 6;
    const int k0 = blockIdx.y * 32 + q * 8;
    float g[8];
    #pragma unroll
    for (int kk = 0; kk < 8; ++kk) g[kk] = __expf(f2[i*NN + k0 + kk] - m);
    F16x8U u;
    #pragma unroll
    for (int kk = 0; kk < 8; ++kk) {
      float h = hidden[((size_t)i*NN + k0 + kk) * REPR + l];
      u.e[kk] = (f16)(g[kk] * h);
    }
    *(f16x8*)&MT[(size_t)(i*REPR + l) * NN + k0] = u.v;
  } else {
    #pragma unroll
    for (int q = 0; q < 2; ++q) {
      const int k0 = (t * 2 + q) * 8;
      F16x8U u;
      #pragma unroll
      for (int kk = 0; kk < 8; ++kk) u.e[kk] = (f16)__expf(f2[i*NN + k0 + kk] - m);
      *(f16x8*)&MT[(size_t)(512 + i) * NN + k0] = u.v;
    }
  }
}

// ---------- k6: 256x320 GEMM, 16 WAVES (1024 thr), counted-vmcnt dbuf, grid 256 ----------
// Same layout/addressing/swizzle as R17 (zero-conflict proven); waves/CU
// doubled 8->16 at constant 144KB LDS. Staging rate model: 2.45 GB/s/wave ->
// 16 waves/CU = ~10 TB/s -> staging 147MB ~ 15 us. Wave grid 4Mx4N, wave-tile
// 64x80 (acc[4][5] = 80 VGPR). A: 2 chunks/thread; B: 2/thread + 1 extra for
// waves 0-7. Per-wave counted waits: vmcnt(5) / vmcnt(4).
__global__ __launch_bounds__(1024) void k_gemm(const f16* __restrict__ A16,
                                               const f16* __restrict__ MT,
                                               f16* __restrict__ P) {
  __shared__ __align__(16) f16 smA[2][256*64];   // 2 x 32 KB
  __shared__ __align__(16) f16 smB[2][320*64];   // 2 x 40 KB
  const int t = threadIdx.x;
  const int lane = t & 63, wid = t >> 6;         // wid 0..15

  const int lin = blockIdx.x;                    // 0..255
  const int xcd = lin & 7, idx = lin >> 3;       // idx 0..31
  const int jt  = xcd + 8 * (idx / 16);          // 0..15
  const int r   = idx % 16;
  const int ct  = r & 1;                         // 0..1
  const int zt  = r >> 1;                        // 0..7

  const int j0 = jt * 256;
  const int c0 = ct * 320;
  const int kz = zt * 512;                       // 8 K-tiles of 64
  const int NK = 8;

  const char* Ab = (const char*)A16;
  const char* Bb = (const char*)MT;
  size_t ga[2]; int cbA[2];
  #pragma unroll
  for (int q = 0; q < 2; ++q) {                  // A: 2048 chunks, 2/thread
    int ci = q*1024 + t;
    int m = ci >> 3, s = ci & 7;
    int c = s ^ (m & 7);
    ga[q]  = ((size_t)(j0 + m) * NN + kz) * 2 + (size_t)c * 16;
    cbA[q] = (q*1024 + wid*64) * 16;
  }
  size_t gb[3]; int cbB[3];
  #pragma unroll
  for (int q = 0; q < 3; ++q) {                  // B: 2560 chunks; q=2 only wid<8
    int ci = (q < 2) ? (q*1024 + t) : (2048 + (t & 511));
    int m = ci >> 3, s = ci & 7;
    int c = s ^ (m & 7);
    gb[q]  = ((size_t)(c0 + m) * NN + kz) * 2 + (size_t)c * 16;
    cbB[q] = (q < 2) ? (q*1024 + wid*64) * 16 : (2048 + wid*64) * 16;
  }

  const int frow = lane & 15, kg = lane >> 4;
  const int wr = wid >> 2, wc = wid & 3;         // 4 x 4 wave grid
  int arow[4], brow[5], soff[2];
  #pragma unroll
  for (int mi = 0; mi < 4; ++mi) arow[mi] = (wr*64 + mi*16 + frow) * 128;  // bytes
  #pragma unroll
  for (int ni = 0; ni < 5; ++ni) brow[ni] = (wc*80 + ni*16 + frow) * 128;  // bytes
  #pragma unroll
  for (int kk = 0; kk < 2; ++kk) soff[kk] = ((kk*4 + kg) ^ (frow & 7)) * 16;

#define STAGE(BUF, KT) do { \
    const size_t kb_ = (size_t)(KT) * 128;  /* 64 f16 */ \
    _Pragma("unroll") \
    for (int q = 0; q < 2; ++q) \
      __builtin_amdgcn_global_load_lds( \
        (const __attribute__((address_space(1))) void*)(Ab + ga[q] + kb_), \
        (__attribute__((address_space(3))) void*)((char*)smA[BUF] + cbA[q]), 16, 0, 0); \
    _Pragma("unroll") \
    for (int q = 0; q < 2; ++q) \
      __builtin_amdgcn_global_load_lds( \
        (const __attribute__((address_space(1))) void*)(Bb + gb[q] + kb_), \
        (__attribute__((address_space(3))) void*)((char*)smB[BUF] + cbB[q]), 16, 0, 0); \
    if (wid < 8) \
      __builtin_amdgcn_global_load_lds( \
        (const __attribute__((address_space(1))) void*)(Bb + gb[2] + kb_), \
        (__attribute__((address_space(3))) void*)((char*)smB[BUF] + cbB[2]), 16, 0, 0); \
  } while (0)

  f32x4 acc[4][5] = {};

  STAGE(0, 0);
  #pragma unroll 1
  for (int kt = 0; kt < NK; ++kt) {
    const int cur = kt & 1;
    if (kt + 1 < NK) {
      STAGE(cur ^ 1, kt + 1);
      if (wid < 8) asm volatile("s_waitcnt vmcnt(5)" ::: "memory");
      else         asm volatile("s_waitcnt vmcnt(4)" ::: "memory");
    } else {
      asm volatile("s_waitcnt vmcnt(0)" ::: "memory");
    }
    __builtin_amdgcn_s_barrier();
    const char* bufA = (const char*)smA[cur];
    const char* bufB = (const char*)smB[cur];
    #pragma unroll
    for (int kk = 0; kk < 2; ++kk) {
      f16x8 b[5], a;
      #pragma unroll
      for (int ni = 0; ni < 5; ++ni)
        b[ni] = *(const f16x8*)(bufB + brow[ni] + soff[kk]);
      #pragma unroll
      for (int mi = 0; mi < 4; ++mi) {
        a = *(const f16x8*)(bufA + arow[mi] + soff[kk]);
        #pragma unroll
        for (int ni = 0; ni < 5; ++ni)
          acc[mi][ni] = __builtin_amdgcn_mfma_f32_16x16x32_f16(a, b[ni], acc[mi][ni], 0, 0, 0);
      }
    }
    __builtin_amdgcn_s_barrier();
  }

  f16* Pz = P + (size_t)zt * PLANE_ELEMS;
  #pragma unroll
  for (int mi = 0; mi < 4; ++mi) {
    const int orow = j0 + wr*64 + mi*16 + kg*4;
    #pragma unroll
    for (int ni = 0; ni < 5; ++ni) {
      const int ocol = c0 + wc*80 + ni*16 + frow;
      if (ocol < 520) {
        #pragma unroll
        for (int r4 = 0; r4 < 4; ++r4)
          Pz[(size_t)(orow + r4) * NCOLP + ocol] = (f16)acc[mi][ni][r4];
      }
    }
  }
#undef STAGE
}

// ---------- k7: vectorized div — 8 cols/thread, f16x8 plane loads ----------
__global__ __launch_bounds__(256) void k_div(const f16* __restrict__ P,
                                             float* __restrict__ out) {
  const int gid = blockIdx.x * 256 + threadIdx.x;   // 262,144
  const int j = gid >> 6, c8 = gid & 63;            // row, 8-col group
  const int i = c8 >> 3;                            // head of this col group
  const size_t rc = (size_t)j*NCOLP + c8*8;
  const size_t rd = (size_t)j*NCOLP + 512 + i;
  float num[8] = {0,0,0,0,0,0,0,0};
  float den = 0.f;
  #pragma unroll
  for (int z = 0; z < KSPLIT; ++z) {
    const f16* Pz = P + (size_t)z * PLANE_ELEMS;
    f16x8 v = *(const f16x8*)&Pz[rc];
    #pragma unroll
    for (int e = 0; e < 8; ++e) num[e] += (float)v[e];
    den += (float)Pz[rd];
  }
  const float inv = 1.f / den;
  float4 o0 = make_float4(num[0]*inv, num[1]*inv, num[2]*inv, num[3]*inv);
  float4 o1 = make_float4(num[4]*inv, num[5]*inv, num[6]*inv, num[7]*inv);
  float* ob = out + (size_t)j*512 + c8*8;
  *(float4*)ob = o0;
  *(float4*)(ob + 4) = o1;
}

extern "C" void kernel_launch(void* const* d_in, const int* in_sizes, int n_in,
                              void* d_out, int out_size, void* d_ws, size_t ws_size,
                              hipStream_t stream) {
  const float* node = (const float*)d_in[0];
  const float* adj  = (const float*)d_in[1];
  const float* W    = (const float*)d_in[2];
  const float* sa   = (const float*)d_in[3];
  float* out = (float*)d_out;
  char* ws = (char*)d_ws;
  if (ws_size < (size_t)WS_END) return;

  float* hidden = (float*)(ws + WS_HID);
  float* f2     = (float*)(ws + WS_F2);
  f16*   A16    = (f16*)(ws + WS_A16);
  f16*   MT     = (f16*)(ws + WS_MT);
  f16*   P      = (f16*)(ws + WS_P);

  k_pre   <<<dim3(9216),      256, 0, stream>>>(node, W, sa, adj, hidden, f2, A16);
  k_mt    <<<dim3(8, 129),    256, 0, stream>>>(hidden, f2, MT);
  k_gemm  <<<dim3(256),      1024, 0, stream>>>(A16, MT, P);
  k_div   <<<dim3(1024),      256, 0, stream>>>(P, out);
}